// Round 4
// baseline (199.145 us; speedup 1.0000x reference)
//
#include <hip/hip_runtime.h>

// RNN_classifier: L=128 sequential steps over D=262144 independent columns,
// then out[t] = sigmoid(dot(x_bar[t], fc_w) + fc_b), out_size = 128 (fp32).
//
// R4: R1's main kernel (proven fastest: float2/thread, 512x256, depth-1
// prefetch) + fused finish via last-block-done atomic (kills the second
// launch + gap). Memory-bound at ~5.9 TB/s effective; floor ~107 us.

#define L     128
#define DCOLS 262144
#define TPB   256
#define NWAVE (TPB / 64)
#define NBLK  (DCOLS / (2 * TPB))      // 512 blocks, float2 per thread
#define PART_BYTES (NBLK * L * 4)      // 256 KB

__device__ __forceinline__ float wred(float v) {
#pragma unroll
    for (int o = 32; o > 0; o >>= 1) v += __shfl_xor(v, o, 64);
    return v;
}

__device__ __forceinline__ float rcpf(float x) { return __builtin_amdgcn_rcpf(x); }

__device__ __forceinline__ float ftanh(float a) {
    a = fminf(fmaxf(a, -15.f), 15.f);          // avoid exp overflow -> NaN
    float e = __expf(-2.f * a);                // v_exp_f32
    return (1.f - e) * rcpf(1.f + e);
}

__device__ __forceinline__ float fsig(float z) {
    return rcpf(1.f + __expf(-z));             // inf-safe: 1/(1+inf) = 0
}

__global__ __launch_bounds__(TPB) void rnn_main(
    const float* __restrict__ x,  const float* __restrict__ wx,
    const float* __restrict__ wg, const float* __restrict__ wu,
    const float* __restrict__ m,  const float* __restrict__ fcw,
    const float* __restrict__ fcb,
    float* __restrict__ part, unsigned int* __restrict__ counter,
    float* __restrict__ out)
{
    __shared__ float lacc[NWAVE][L];
    __shared__ int   sIsLast;
    const int tid  = threadIdx.x;
    const int lane = tid & 63;
    const int wid  = tid >> 6;
    const int col2 = blockIdx.x * TPB + tid;   // float2 column index
    const int stride2 = DCOLS / 2;

    const float2* px  = (const float2*)x  + col2;
    const float2* pm  = (const float2*)m  + col2;
    const float2* pwx = (const float2*)wx + col2;
    const float2* pwu = (const float2*)wu + col2;
    const float2* pwg = (const float2*)wg + col2;

    const float2 fw = ((const float2*)fcw)[col2];

    // ---- t = 0 ----
    float2 x0  = px[0];
    float2 wx0 = pwx[0];
    float2 wg0 = pwg[0];

    float2 h0, h, xb;
    h0.x = ftanh(x0.x * wx0.x);  h0.y = ftanh(x0.y * wx0.y);
    xb.x = h0.x * wg0.x + x0.x;  xb.y = h0.y * wg0.y + x0.y;   // xbar1
    h = h0;

    {   // x_bar[0] = x[0]
        float s = wred(x0.x * fw.x + x0.y * fw.y);
        if (lane == 0) lacc[wid][0] = s;
    }

    // prefetch t = 1
    float2 xn  = px[stride2];
    float2 mn  = pm[stride2];
    float2 wxn = pwx[stride2];
    float2 wun = pwu[stride2];
    float2 wgn = pwg[stride2];

    for (int t = 1; t < L; ++t) {
        float2 xc = xn, mc = mn, wxc = wxn, wuc = wun, wgc = wgn;
        if (t < L - 1) {                       // prefetch t+1 while computing t
            const int o = (t + 1) * stride2;
            xn = px[o]; mn = pm[o]; wxn = pwx[o]; wun = pwu[o]; wgn = pwg[o];
        }

        // emit pre-update carry: x_bar[t]
        float s = wred(xb.x * fw.x + xb.y * fw.y);
        if (lane == 0) lacc[wid][t] = s;

        // carry update with row-t data
        {
            float xt = xc.x * mc.x + xb.x * (1.f - mc.x);
            float u  = ftanh(xt * wxc.x);
            float f  = fsig(h.x + u * wuc.x) * mc.x;
            float hn = f * h.x + (1.f - f) * u;
            h.x  = fmaxf(hn, h0.x);            // h0 + relu(h - h0)
            xb.x = h.x * wgc.x + xt;
        }
        {
            float xt = xc.y * mc.y + xb.y * (1.f - mc.y);
            float u  = ftanh(xt * wxc.y);
            float f  = fsig(h.y + u * wuc.y) * mc.y;
            float hn = f * h.y + (1.f - f) * u;
            h.y  = fmaxf(hn, h0.y);
            xb.y = h.y * wgc.y + xt;
        }
    }

    __syncthreads();
    if (tid < L) {
        float s = 0.f;
#pragma unroll
        for (int w = 0; w < NWAVE; ++w) s += lacc[w][tid];
        part[tid * NBLK + blockIdx.x] = s;     // transposed: [t][block]
    }

    // ---- last-block-done fused finish ----
    __threadfence();                           // make part[] visible device-wide
    __syncthreads();
    if (tid == 0) {
        unsigned int old = atomicAdd(counter, 1u);
        sIsLast = (old == NBLK - 1);
    }
    __syncthreads();
    if (!sIsLast) return;

    __threadfence();                           // acquire all blocks' part[]
    const float bias = fcb[0];
    // 4 waves x 32 t's each; per t: 8 coalesced 256B loads + wave reduce
    for (int t = wid * (L / NWAVE); t < (wid + 1) * (L / NWAVE); ++t) {
        float s = 0.f;
#pragma unroll
        for (int i = 0; i < NBLK / 64; ++i) s += part[t * NBLK + i * 64 + lane];
        s = wred(s);
        if (lane == 0) out[t] = fsig(s + bias);
    }
}

extern "C" void kernel_launch(void* const* d_in, const int* in_sizes, int n_in,
                              void* d_out, int out_size, void* d_ws, size_t ws_size,
                              hipStream_t stream) {
    // setup_inputs order: x, weight_x, weight_g, weight_u, mask, fc_w, fc_b
    const float* x   = (const float*)d_in[0];
    const float* wx  = (const float*)d_in[1];
    const float* wg  = (const float*)d_in[2];
    const float* wu  = (const float*)d_in[3];
    const float* m   = (const float*)d_in[4];
    const float* fcw = (const float*)d_in[5];
    const float* fcb = (const float*)d_in[6];
    float* out  = (float*)d_out;
    float* part = (float*)d_ws;                             // 256 KB
    unsigned int* counter = (unsigned int*)((char*)d_ws + PART_BYTES);

    hipMemsetAsync(counter, 0, sizeof(unsigned int), stream);  // in-graph reset
    rnn_main<<<NBLK, TPB, 0, stream>>>(x, wx, wg, wu, m, fcw, fcb,
                                       part, counter, out);
}

// Round 5
// 113.467 us; speedup vs baseline: 1.7551x; 1.7551x over previous
//
#include <hip/hip_runtime.h>

// RNN_classifier: L=128 sequential steps over D=262144 independent columns,
// then out[t] = sigmoid(dot(x_bar[t], fc_w) + fc_b), out_size = 128 (fp32).
//
// R5: revert R4's fused finish (device-scope fences cost ~85 us). R1 base
// (float2/thread, 512x256, best measured: 114.6 us = 93% of 6.29 TB/s
// copy ceiling on 671 MB) + depth-2 register prefetch (40 KB/CU in flight,
// 2x the BW*latency product) as the last latency-slack lever.

#define L     128
#define DCOLS 262144
#define TPB   256
#define NWAVE (TPB / 64)
#define NBLK  (DCOLS / (2 * TPB))   // 512 blocks, float2 per thread

__device__ __forceinline__ float wred(float v) {
#pragma unroll
    for (int o = 32; o > 0; o >>= 1) v += __shfl_xor(v, o, 64);
    return v;
}

__device__ __forceinline__ float rcpf(float x) { return __builtin_amdgcn_rcpf(x); }

__device__ __forceinline__ float ftanh(float a) {
    a = fminf(fmaxf(a, -15.f), 15.f);          // avoid exp overflow -> NaN
    float e = __expf(-2.f * a);                // v_exp_f32
    return (1.f - e) * rcpf(1.f + e);
}

__device__ __forceinline__ float fsig(float z) {
    return rcpf(1.f + __expf(-z));             // inf-safe: 1/(1+inf) = 0
}

__global__ __launch_bounds__(TPB) void rnn_main(
    const float* __restrict__ x,  const float* __restrict__ wx,
    const float* __restrict__ wg, const float* __restrict__ wu,
    const float* __restrict__ m,  const float* __restrict__ fcw,
    float* __restrict__ part)
{
    __shared__ float lacc[NWAVE][L];
    const int tid  = threadIdx.x;
    const int lane = tid & 63;
    const int wid  = tid >> 6;
    const int col2 = blockIdx.x * TPB + tid;   // float2 column index
    const int stride2 = DCOLS / 2;

    const float2* px  = (const float2*)x  + col2;
    const float2* pm  = (const float2*)m  + col2;
    const float2* pwx = (const float2*)wx + col2;
    const float2* pwu = (const float2*)wu + col2;
    const float2* pwg = (const float2*)wg + col2;

    const float2 fw = ((const float2*)fcw)[col2];

    // ---- t = 0 ----
    float2 x0  = px[0];
    float2 wx0 = pwx[0];
    float2 wg0 = pwg[0];

    float2 h0, h, xb;
    h0.x = ftanh(x0.x * wx0.x);  h0.y = ftanh(x0.y * wx0.y);
    xb.x = h0.x * wg0.x + x0.x;  xb.y = h0.y * wg0.y + x0.y;   // xbar1
    h = h0;

    {   // x_bar[0] = x[0]
        float s = wred(x0.x * fw.x + x0.y * fw.y);
        if (lane == 0) lacc[wid][0] = s;
    }

#define STEP(T, XR, MR, WXR, WUR, WGR)                                   \
    {                                                                    \
        float s = wred(xb.x * fw.x + xb.y * fw.y);  /* x_bar[T] */       \
        if (lane == 0) lacc[wid][(T)] = s;                               \
        {                                                                \
            float xt = (XR).x * (MR).x + xb.x * (1.f - (MR).x);          \
            float u  = ftanh(xt * (WXR).x);                              \
            float f  = fsig(h.x + u * (WUR).x) * (MR).x;                 \
            float hn = f * h.x + (1.f - f) * u;                          \
            h.x  = fmaxf(hn, h0.x);            /* h0 + relu(h-h0) */     \
            xb.x = h.x * (WGR).x + xt;                                   \
        }                                                                \
        {                                                                \
            float xt = (XR).y * (MR).y + xb.y * (1.f - (MR).y);          \
            float u  = ftanh(xt * (WXR).y);                              \
            float f  = fsig(h.y + u * (WUR).y) * (MR).y;                 \
            float hn = f * h.y + (1.f - f) * u;                          \
            h.y  = fmaxf(hn, h0.y);                                      \
            xb.y = h.y * (WGR).y + xt;                                   \
        }                                                                \
    }

    // depth-2 prefetch: row 1 in A, row 2 in B
    float2 Ax = px[1 * stride2], Am = pm[1 * stride2], Awx = pwx[1 * stride2],
           Awu = pwu[1 * stride2], Awg = pwg[1 * stride2];
    float2 Bx = px[2 * stride2], Bm = pm[2 * stride2], Bwx = pwx[2 * stride2],
           Bwu = pwu[2 * stride2], Bwg = pwg[2 * stride2];

    int t = 1;
    for (; t + 1 < L; t += 2) {
        {   // step t (A regs), prefetch t+2 into A
            float2 cx = Ax, cm = Am, cwx = Awx, cwu = Awu, cwg = Awg;
            if (t + 2 < L) {
                const int o = (t + 2) * stride2;
                Ax = px[o]; Am = pm[o]; Awx = pwx[o]; Awu = pwu[o]; Awg = pwg[o];
            }
            STEP(t, cx, cm, cwx, cwu, cwg);
        }
        {   // step t+1 (B regs), prefetch t+3 into B
            float2 cx = Bx, cm = Bm, cwx = Bwx, cwu = Bwu, cwg = Bwg;
            if (t + 3 < L) {
                const int o = (t + 3) * stride2;
                Bx = px[o]; Bm = pm[o]; Bwx = pwx[o]; Bwu = pwu[o]; Bwg = pwg[o];
            }
            STEP(t + 1, cx, cm, cwx, cwu, cwg);
        }
    }
    // t == 127: last step, data in A (prefetched at t=125)
    STEP(t, Ax, Am, Awx, Awu, Awg);
#undef STEP

    __syncthreads();
    if (tid < L) {
        float s = 0.f;
#pragma unroll
        for (int w = 0; w < NWAVE; ++w) s += lacc[w][tid];
        part[blockIdx.x * L + tid] = s;        // coalesced per-block rows
    }
}

__global__ __launch_bounds__(64) void rnn_finish(
    const float* __restrict__ part, const float* __restrict__ fcb,
    float* __restrict__ out)
{
    const int t    = blockIdx.x;   // 0..127
    const int lane = threadIdx.x;  // 64
    float s = 0.f;
#pragma unroll
    for (int i = 0; i < NBLK / 64; ++i) s += part[(i * 64 + lane) * L + t];
#pragma unroll
    for (int o = 32; o > 0; o >>= 1) s += __shfl_xor(s, o, 64);
    if (lane == 0) out[t] = fsig(s + fcb[0]);
}

extern "C" void kernel_launch(void* const* d_in, const int* in_sizes, int n_in,
                              void* d_out, int out_size, void* d_ws, size_t ws_size,
                              hipStream_t stream) {
    // setup_inputs order: x, weight_x, weight_g, weight_u, mask, fc_w, fc_b
    const float* x   = (const float*)d_in[0];
    const float* wx  = (const float*)d_in[1];
    const float* wg  = (const float*)d_in[2];
    const float* wu  = (const float*)d_in[3];
    const float* m   = (const float*)d_in[4];
    const float* fcw = (const float*)d_in[5];
    const float* fcb = (const float*)d_in[6];
    float* out  = (float*)d_out;
    float* part = (float*)d_ws;    // NBLK * L floats = 256 KB

    rnn_main<<<NBLK, TPB, 0, stream>>>(x, wx, wg, wu, m, fcw, part);
    rnn_finish<<<L, 64, 0, stream>>>(part, fcb, out);
}